// Round 2
// baseline (1830.144 us; speedup 1.0000x reference)
//
#include <hip/hip_runtime.h>
#include <hip/hip_bf16.h>

// Grid LSTM (tanh grid-RNN), D=2, S=T=48, B=32, H=256. f32 in/out (per
// reference dtypes); bf16 MFMA internally. Persistent systolic columns with
// agent-scope flag sync; U/W1 held in VGPRs as pre-swizzled MFMA B-frags.

typedef short short8 __attribute__((ext_vector_type(8)));
typedef float f32x4 __attribute__((ext_vector_type(4)));

static constexpr size_t UF_OFF    = 0;                          // 512 KiB U frags (bf16)
static constexpr size_t WF_OFF    = 512u * 1024;                // 256 KiB W frags (bf16)
static constexpr size_t SRCW_OFF  = 768u * 1024;                // 1.5 MiB f32
static constexpr size_t TRGW_OFF  = SRCW_OFF + 48u * 32 * 256 * 4;
static constexpr size_t FLAG0_OFF = TRGW_OFF + 48u * 32 * 256 * 4;
static constexpr size_t FLAG1_OFF = FLAG0_OFF + 48u * 48 * 4;

#define MFMA16(a, b, c) __builtin_amdgcn_mfma_f32_16x16x32_bf16(a, b, c, 0, 0, 0)

__device__ __forceinline__ short f2bf(float f) {
  __hip_bfloat16 h = __float2bfloat16(f);
  return __builtin_bit_cast(short, h);
}

__device__ __forceinline__ size_t plane_off(int d, int s, int t, int c) {
  return (size_t)(((d * 48 + s) * 48 + t) * 2 + c) * 8192u;  // f32 elements
}

__device__ __forceinline__ void wait_ge(int* p, int v) {
  while (__hip_atomic_load(p, __ATOMIC_RELAXED, __HIP_MEMORY_SCOPE_AGENT) < v)
    __builtin_amdgcn_s_sleep(1);
}

__device__ __forceinline__ float fast_tanh(float x) {
  float e = exp2f(x * 2.88539008f);
  return 1.f - __fdividef(2.f, e + 1.f);
}

// ---------------------------------------------------------------------------
// Kernel 1: U (2,512,256) f32 and W (2,256,256) f32 -> bf16 MFMA B-fragments.
// Per (d, nh, wave) region, frag f=nt*K+ks: lane holds B[k=ks*32+q*8+j][n].
// ---------------------------------------------------------------------------
__global__ void preswizzle(const float* __restrict__ U,
                           const float* __restrict__ W,
                           char* __restrict__ ws) {
  int gid = blockIdx.x * 256 + threadIdx.x;
  if (gid < 32768) {  // U: 2*512*256/8 chunks
    int r = gid >> 11;                 // (d,nh,w)
    int d = r >> 3, nh = (r >> 2) & 1, w = r & 3;
    int c = gid & 2047;
    int f = c >> 6, lane = c & 63;     // f = nt*16 + ks
    int nt = f >> 4, ks = f & 15;
    int kbase = ks * 32 + (lane >> 4) * 8;
    int n = nh * 128 + w * 32 + nt * 16 + (lane & 15);
    const float* sp = U + (size_t)d * 512 * 256 + n;
    short8 v;
#pragma unroll
    for (int j = 0; j < 8; ++j) v[j] = f2bf(sp[(size_t)(kbase + j) * 256]);
    *(short8*)(ws + UF_OFF + (size_t)gid * 16) = v;
  } else {            // W: 2*256*256/8 chunks
    int idx = gid - 32768;
    int r = idx >> 10;
    int d = r >> 3, nh = (r >> 2) & 1, w = r & 3;
    int c = idx & 1023;
    int f = c >> 6, lane = c & 63;     // f = nt*8 + ks
    int nt = f >> 3, ks = f & 7;
    int kbase = ks * 32 + (lane >> 4) * 8;
    int n = nh * 128 + w * 32 + nt * 16 + (lane & 15);
    const float* sp = W + (size_t)d * 256 * 256 + n;
    short8 v;
#pragma unroll
    for (int j = 0; j < 8; ++j) v[j] = f2bf(sp[(size_t)(kbase + j) * 256]);
    *(short8*)(ws + WF_OFF + (size_t)idx * 16) = v;
  }
}

// ---------------------------------------------------------------------------
// Kernel 2: SRCW[s] = src[s]@W0 + b0 ; TRGW[t] = trg[t]@W0 + b0  (f32)
// ---------------------------------------------------------------------------
__global__ __launch_bounds__(256, 1) void precompute_xw(
    const float* __restrict__ src, const float* __restrict__ trg,
    const float* __restrict__ bvec, char* __restrict__ ws) {
  __shared__ __align__(16) char lds[32 * 528];
  const int bid = blockIdx.x;
  const int i = bid >> 1, nh = bid & 1;
  const int tid = threadIdx.x;
  const int w = tid >> 6, lane = tid & 63;
  const int alane = lane & 15, q = lane >> 4;

  short8 bw[2][8];
  {
    const char* wb = ws + WF_OFF + (size_t)(nh * 4 + w) * 16384u + (size_t)lane * 16;
#pragma unroll
    for (int nt = 0; nt < 2; ++nt)
#pragma unroll
      for (int ks = 0; ks < 8; ++ks)
        bw[nt][ks] = *(const short8*)(wb + (nt * 8 + ks) * 1024);
  }

  const float* plane = (i < 48) ? src + (size_t)i * 8192 : trg + (size_t)(i - 48) * 8192;
#pragma unroll
  for (int it = 0; it < 4; ++it) {
    int gid = it * 256 + tid;
    int row = gid >> 5, c = gid & 31;
    const float* p = plane + row * 256 + c * 8;
    short8 v;
#pragma unroll
    for (int j = 0; j < 8; ++j) v[j] = f2bf(p[j]);
    *(short8*)(lds + row * 528 + c * 16) = v;
  }
  __syncthreads();

  const f32x4 zf = {0.f, 0.f, 0.f, 0.f};
  f32x4 acc[2][2];
  acc[0][0] = zf; acc[0][1] = zf; acc[1][0] = zf; acc[1][1] = zf;
  const char* ar0 = lds + alane * 528 + q * 16;
  const char* ar1 = lds + (alane + 16) * 528 + q * 16;
#pragma unroll
  for (int ks = 0; ks < 8; ++ks) {
    short8 a0 = *(const short8*)(ar0 + ks * 64);
    short8 a1 = *(const short8*)(ar1 + ks * 64);
#pragma unroll
    for (int nt = 0; nt < 2; ++nt) {
      acc[0][nt] = MFMA16(a0, bw[nt][ks], acc[0][nt]);
      acc[1][nt] = MFMA16(a1, bw[nt][ks], acc[1][nt]);
    }
  }

  const int n0 = nh * 128 + w * 32 + alane;
  float bs[2] = {bvec[n0], bvec[n0 + 16]};
  float* dst = (float*)(ws + (i < 48 ? SRCW_OFF : TRGW_OFF)) +
               (size_t)(i < 48 ? i : i - 48) * 8192;
#pragma unroll
  for (int mt = 0; mt < 2; ++mt)
#pragma unroll
    for (int nt = 0; nt < 2; ++nt)
#pragma unroll
      for (int rr = 0; rr < 4; ++rr) {
        int row = mt * 16 + q * 4 + rr;
        dst[row * 256 + n0 + nt * 16] = acc[mt][nt][rr] + bs[nt];
      }
}

// ---------------------------------------------------------------------------
// Kernel 3: persistent systolic grid. 192 blocks = (d, t, nh). Each walks s.
// ---------------------------------------------------------------------------
__global__ __launch_bounds__(256, 1) void grid_main(
    float* __restrict__ out, const float* __restrict__ bvec,
    char* __restrict__ ws) {
  __shared__ __align__(16) char lds[32 * 1040];  // 32 rows x (64*16B + pad)
  const int bid = blockIdx.x;
  const int d = bid / 96;
  const int r = bid % 96;
  const int t = r >> 1, nh = r & 1;
  const int tid = threadIdx.x;
  const int w = tid >> 6, lane = tid & 63;
  const int alane = lane & 15, q = lane >> 4;

  int* flag0 = (int*)(ws + FLAG0_OFF);
  int* flag1 = (int*)(ws + FLAG1_OFF);
  const float* SRCW = (const float*)(ws + SRCW_OFF);
  const float* TRGW = (const float*)(ws + TRGW_OFF);

  // U fragments for this (d, nh, wave): resident in VGPRs for all 48 cells.
  short8 bu[2][16];
  {
    const char* ub = ws + UF_OFF + (size_t)((d * 2 + nh) * 4 + w) * 32768u + (size_t)lane * 16;
#pragma unroll
    for (int nt = 0; nt < 2; ++nt)
#pragma unroll
      for (int ks = 0; ks < 16; ++ks)
        bu[nt][ks] = *(const short8*)(ub + (nt * 16 + ks) * 1024);
  }
  short8 bw[2][8];
  float bs1[2] = {0.f, 0.f};
  if (d == 1) {
    const char* wb = ws + WF_OFF + (size_t)((2 + nh) * 4 + w) * 16384u + (size_t)lane * 16;
#pragma unroll
    for (int nt = 0; nt < 2; ++nt)
#pragma unroll
      for (int ks = 0; ks < 8; ++ks)
        bw[nt][ks] = *(const short8*)(wb + (nt * 8 + ks) * 1024);
    int bn = nh * 128 + w * 32 + alane;
    bs1[0] = bvec[256 + bn];
    bs1[1] = bvec[256 + bn + 16];
  }

  const char* ar0 = lds + alane * 1040 + q * 16;
  const char* ar1 = lds + (alane + 16) * 1040 + q * 16;
  const int n0 = nh * 128 + w * 32 + alane;
  const f32x4 zf = {0.f, 0.f, 0.f, 0.f};

  for (int s = 0; s < 48; ++s) {
    f32x4 acc[2][2];
    acc[0][0] = zf; acc[0][1] = zf; acc[1][0] = zf; acc[1][1] = zf;

    if (d == 0) {
      if (s > 0) wait_ge(&flag0[(s - 1) * 48 + t], 2);
      if (t > 0) wait_ge(&flag0[s * 48 + (t - 1)], 2);
      __builtin_amdgcn_fence(__ATOMIC_ACQUIRE, "agent");
      {  // stage A = [up | left] (zeros at boundary), f32 -> bf16
        const float* pu = (s > 0) ? out + plane_off(0, s - 1, t, 0) : nullptr;
        const float* pl = (t > 0) ? out + plane_off(0, s, t - 1, 0) : nullptr;
#pragma unroll
        for (int it = 0; it < 8; ++it) {
          int gid = it * 256 + tid;
          int p = gid >> 10, row = (gid >> 5) & 31, c = gid & 31;
          const float* pp = p ? pl : pu;
          short8 v = {0, 0, 0, 0, 0, 0, 0, 0};
          if (pp) {
#pragma unroll
            for (int j = 0; j < 8; ++j) v[j] = f2bf(pp[row * 256 + c * 8 + j]);
          }
          *(short8*)(lds + row * 1040 + (p * 32 + c) * 16) = v;
        }
      }
      __syncthreads();
#pragma unroll
      for (int ks = 0; ks < 16; ++ks) {
        short8 a0 = *(const short8*)(ar0 + ks * 64);
        short8 a1 = *(const short8*)(ar1 + ks * 64);
#pragma unroll
        for (int nt = 0; nt < 2; ++nt) {
          acc[0][nt] = MFMA16(a0, bu[nt][ks], acc[0][nt]);
          acc[1][nt] = MFMA16(a1, bu[nt][ks], acc[1][nt]);
        }
      }
      float* hxp = out + plane_off(0, s, t, 0);
      float* hyp = out + plane_off(0, s, t, 1);
      const float* sxp = SRCW + (size_t)s * 8192;
      const float* syp = TRGW + (size_t)t * 8192;
#pragma unroll
      for (int mt = 0; mt < 2; ++mt)
#pragma unroll
        for (int nt = 0; nt < 2; ++nt)
#pragma unroll
          for (int rr = 0; rr < 4; ++rr) {
            int row = mt * 16 + q * 4 + rr;
            int n = n0 + nt * 16;
            float tv = acc[mt][nt][rr];
            hxp[row * 256 + n] = fast_tanh(sxp[row * 256 + n] + tv);
            hyp[row * 256 + n] = fast_tanh(syp[row * 256 + n] + tv);
          }
    } else {
      // --- layer 1: X/Y projections first (layer-0 runs ahead), then temp ---
      wait_ge(&flag0[s * 48 + t], 2);
      __builtin_amdgcn_fence(__ATOMIC_ACQUIRE, "agent");
      {  // stage [hx0 | hy0], f32 -> bf16
        const float* px = out + plane_off(0, s, t, 0);
        const float* py = out + plane_off(0, s, t, 1);
#pragma unroll
        for (int it = 0; it < 8; ++it) {
          int gid = it * 256 + tid;
          int p = gid >> 10, row = (gid >> 5) & 31, c = gid & 31;
          const float* pp = p ? py : px;
          short8 v;
#pragma unroll
          for (int j = 0; j < 8; ++j) v[j] = f2bf(pp[row * 256 + c * 8 + j]);
          *(short8*)(lds + row * 1040 + (p * 32 + c) * 16) = v;
        }
      }
      __syncthreads();
      f32x4 accx[2][2], accy[2][2];
      accx[0][0] = zf; accx[0][1] = zf; accx[1][0] = zf; accx[1][1] = zf;
      accy[0][0] = zf; accy[0][1] = zf; accy[1][0] = zf; accy[1][1] = zf;
#pragma unroll
      for (int ks = 0; ks < 8; ++ks) {
        short8 ax0 = *(const short8*)(ar0 + ks * 64);
        short8 ax1 = *(const short8*)(ar1 + ks * 64);
        short8 ay0 = *(const short8*)(ar0 + 512 + ks * 64);
        short8 ay1 = *(const short8*)(ar1 + 512 + ks * 64);
#pragma unroll
        for (int nt = 0; nt < 2; ++nt) {
          accx[0][nt] = MFMA16(ax0, bw[nt][ks], accx[0][nt]);
          accx[1][nt] = MFMA16(ax1, bw[nt][ks], accx[1][nt]);
          accy[0][nt] = MFMA16(ay0, bw[nt][ks], accy[0][nt]);
          accy[1][nt] = MFMA16(ay1, bw[nt][ks], accy[1][nt]);
        }
      }
      __syncthreads();  // done reading LDS; safe to restage
      if (s > 0) wait_ge(&flag1[(s - 1) * 48 + t], 2);
      if (t > 0) wait_ge(&flag1[s * 48 + (t - 1)], 2);
      __builtin_amdgcn_fence(__ATOMIC_ACQUIRE, "agent");
      {  // stage A = [up1 | left1], f32 -> bf16
        const float* pu = (s > 0) ? out + plane_off(1, s - 1, t, 0) : nullptr;
        const float* pl = (t > 0) ? out + plane_off(1, s, t - 1, 0) : nullptr;
#pragma unroll
        for (int it = 0; it < 8; ++it) {
          int gid = it * 256 + tid;
          int p = gid >> 10, row = (gid >> 5) & 31, c = gid & 31;
          const float* pp = p ? pl : pu;
          short8 v = {0, 0, 0, 0, 0, 0, 0, 0};
          if (pp) {
#pragma unroll
            for (int j = 0; j < 8; ++j) v[j] = f2bf(pp[row * 256 + c * 8 + j]);
          }
          *(short8*)(lds + row * 1040 + (p * 32 + c) * 16) = v;
        }
      }
      __syncthreads();
#pragma unroll
      for (int ks = 0; ks < 16; ++ks) {
        short8 a0 = *(const short8*)(ar0 + ks * 64);
        short8 a1 = *(const short8*)(ar1 + ks * 64);
#pragma unroll
        for (int nt = 0; nt < 2; ++nt) {
          acc[0][nt] = MFMA16(a0, bu[nt][ks], acc[0][nt]);
          acc[1][nt] = MFMA16(a1, bu[nt][ks], acc[1][nt]);
        }
      }
      float* hxp = out + plane_off(1, s, t, 0);
      float* hyp = out + plane_off(1, s, t, 1);
#pragma unroll
      for (int mt = 0; mt < 2; ++mt)
#pragma unroll
        for (int nt = 0; nt < 2; ++nt)
#pragma unroll
          for (int rr = 0; rr < 4; ++rr) {
            int row = mt * 16 + q * 4 + rr;
            int n = n0 + nt * 16;
            float tv = acc[mt][nt][rr];
            hxp[row * 256 + n] = fast_tanh(accx[mt][nt][rr] + tv + bs1[nt]);
            hyp[row * 256 + n] = fast_tanh(accy[mt][nt][rr] + tv + bs1[nt]);
          }
    }
    __syncthreads();
    if (tid == 0) {
      __builtin_amdgcn_fence(__ATOMIC_RELEASE, "agent");
      int* fp = (d == 0) ? &flag0[s * 48 + t] : &flag1[s * 48 + t];
      __hip_atomic_fetch_add(fp, 1, __ATOMIC_RELEASE, __HIP_MEMORY_SCOPE_AGENT);
    }
  }
}

extern "C" void kernel_launch(void* const* d_in, const int* in_sizes, int n_in,
                              void* d_out, int out_size, void* d_ws, size_t ws_size,
                              hipStream_t stream) {
  const float* src = (const float*)d_in[0];
  const float* trg = (const float*)d_in[1];
  const float* W   = (const float*)d_in[2];
  const float* U   = (const float*)d_in[3];
  const float* bv  = (const float*)d_in[4];
  float* out = (float*)d_out;
  char* ws = (char*)d_ws;

  hipMemsetAsync(ws + FLAG0_OFF, 0, 2u * 48 * 48 * 4, stream);
  preswizzle<<<192, 256, 0, stream>>>(U, W, ws);
  precompute_xw<<<192, 256, 0, stream>>>(src, trg, bv, ws);
  grid_main<<<192, 256, 0, stream>>>(out, bv, ws);
}

// Round 3
// 966.387 us; speedup vs baseline: 1.8938x; 1.8938x over previous
//
#include <hip/hip_runtime.h>
#include <hip/hip_bf16.h>

// Grid LSTM (tanh grid-RNN), D=2, S=T=48, B=32, H=256. f32 in/out; bf16 MFMA
// internally. Persistent systolic columns. Cross-XCD handoff is FENCE-FREE:
// producers write h via cache-bypassing agent atomic stores (-> LLC), order
// with s_waitcnt vmcnt(0), then relaxed flag add; consumers poll relaxed and
// read with plain cached loads (each staged address read once per block per
// launch; dispatch-entry cache invalidation guarantees no stale lines).

typedef short short8 __attribute__((ext_vector_type(8)));
typedef float f32x4 __attribute__((ext_vector_type(4)));

static constexpr size_t UF_OFF    = 0;                          // 512 KiB U frags (bf16)
static constexpr size_t WF_OFF    = 512u * 1024;                // 256 KiB W frags (bf16)
static constexpr size_t SRCW_OFF  = 768u * 1024;                // 1.5 MiB f32
static constexpr size_t TRGW_OFF  = SRCW_OFF + 48u * 32 * 256 * 4;
static constexpr size_t FLAG0_OFF = TRGW_OFF + 48u * 32 * 256 * 4;
static constexpr size_t FLAG1_OFF = FLAG0_OFF + 48u * 48 * 4;

#define MFMA16(a, b, c) __builtin_amdgcn_mfma_f32_16x16x32_bf16(a, b, c, 0, 0, 0)

__device__ __forceinline__ short f2bf(float f) {
  __hip_bfloat16 h = __float2bfloat16(f);
  return __builtin_bit_cast(short, h);
}

__device__ __forceinline__ size_t plane_off(int d, int s, int t, int c) {
  return (size_t)(((d * 48 + s) * 48 + t) * 2 + c) * 8192u;  // f32 elements
}

__device__ __forceinline__ void wait_ge(int* p, int v) {
  while (__hip_atomic_load(p, __ATOMIC_RELAXED, __HIP_MEMORY_SCOPE_AGENT) < v)
    __builtin_amdgcn_s_sleep(1);
  asm volatile("" ::: "memory");  // keep subsequent loads below the spin
}

// write-through to LLC (sc0 sc1): visible agent-wide once vmcnt retires.
__device__ __forceinline__ void st_llc(float* p, float v) {
  __hip_atomic_store(p, v, __ATOMIC_RELAXED, __HIP_MEMORY_SCOPE_AGENT);
}

__device__ __forceinline__ float fast_tanh(float x) {
  float e = exp2f(x * 2.88539008f);
  return 1.f - __fdividef(2.f, e + 1.f);
}

// ---------------------------------------------------------------------------
// Kernel 1: U (2,512,256) f32 and W (2,256,256) f32 -> bf16 MFMA B-fragments.
// ---------------------------------------------------------------------------
__global__ void preswizzle(const float* __restrict__ U,
                           const float* __restrict__ W,
                           char* __restrict__ ws) {
  int gid = blockIdx.x * 256 + threadIdx.x;
  if (gid < 32768) {  // U
    int r = gid >> 11;
    int d = r >> 3, nh = (r >> 2) & 1, w = r & 3;
    int c = gid & 2047;
    int f = c >> 6, lane = c & 63;
    int nt = f >> 4, ks = f & 15;
    int kbase = ks * 32 + (lane >> 4) * 8;
    int n = nh * 128 + w * 32 + nt * 16 + (lane & 15);
    const float* sp = U + (size_t)d * 512 * 256 + n;
    short8 v;
#pragma unroll
    for (int j = 0; j < 8; ++j) v[j] = f2bf(sp[(size_t)(kbase + j) * 256]);
    *(short8*)(ws + UF_OFF + (size_t)gid * 16) = v;
  } else {            // W
    int idx = gid - 32768;
    int r = idx >> 10;
    int d = r >> 3, nh = (r >> 2) & 1, w = r & 3;
    int c = idx & 1023;
    int f = c >> 6, lane = c & 63;
    int nt = f >> 3, ks = f & 7;
    int kbase = ks * 32 + (lane >> 4) * 8;
    int n = nh * 128 + w * 32 + nt * 16 + (lane & 15);
    const float* sp = W + (size_t)d * 256 * 256 + n;
    short8 v;
#pragma unroll
    for (int j = 0; j < 8; ++j) v[j] = f2bf(sp[(size_t)(kbase + j) * 256]);
    *(short8*)(ws + WF_OFF + (size_t)idx * 16) = v;
  }
}

// ---------------------------------------------------------------------------
// Kernel 2: SRCW[s] = src[s]@W0 + b0 ; TRGW[t] = trg[t]@W0 + b0  (f32)
// ---------------------------------------------------------------------------
__global__ __launch_bounds__(256, 1) void precompute_xw(
    const float* __restrict__ src, const float* __restrict__ trg,
    const float* __restrict__ bvec, char* __restrict__ ws) {
  __shared__ __align__(16) char lds[32 * 528];
  const int bid = blockIdx.x;
  const int i = bid >> 1, nh = bid & 1;
  const int tid = threadIdx.x;
  const int w = tid >> 6, lane = tid & 63;
  const int alane = lane & 15, q = lane >> 4;

  short8 bw[2][8];
  {
    const char* wb = ws + WF_OFF + (size_t)(nh * 4 + w) * 16384u + (size_t)lane * 16;
#pragma unroll
    for (int nt = 0; nt < 2; ++nt)
#pragma unroll
      for (int ks = 0; ks < 8; ++ks)
        bw[nt][ks] = *(const short8*)(wb + (nt * 8 + ks) * 1024);
  }

  const float* plane = (i < 48) ? src + (size_t)i * 8192 : trg + (size_t)(i - 48) * 8192;
#pragma unroll
  for (int it = 0; it < 4; ++it) {
    int gid = it * 256 + tid;
    int row = gid >> 5, c = gid & 31;
    const float* p = plane + row * 256 + c * 8;
    short8 v;
#pragma unroll
    for (int j = 0; j < 8; ++j) v[j] = f2bf(p[j]);
    *(short8*)(lds + row * 528 + c * 16) = v;
  }
  __syncthreads();

  const f32x4 zf = {0.f, 0.f, 0.f, 0.f};
  f32x4 acc[2][2];
  acc[0][0] = zf; acc[0][1] = zf; acc[1][0] = zf; acc[1][1] = zf;
  const char* ar0 = lds + alane * 528 + q * 16;
  const char* ar1 = lds + (alane + 16) * 528 + q * 16;
#pragma unroll
  for (int ks = 0; ks < 8; ++ks) {
    short8 a0 = *(const short8*)(ar0 + ks * 64);
    short8 a1 = *(const short8*)(ar1 + ks * 64);
#pragma unroll
    for (int nt = 0; nt < 2; ++nt) {
      acc[0][nt] = MFMA16(a0, bw[nt][ks], acc[0][nt]);
      acc[1][nt] = MFMA16(a1, bw[nt][ks], acc[1][nt]);
    }
  }

  const int n0 = nh * 128 + w * 32 + alane;
  float bs[2] = {bvec[n0], bvec[n0 + 16]};
  float* dst = (float*)(ws + (i < 48 ? SRCW_OFF : TRGW_OFF)) +
               (size_t)(i < 48 ? i : i - 48) * 8192;
#pragma unroll
  for (int mt = 0; mt < 2; ++mt)
#pragma unroll
    for (int nt = 0; nt < 2; ++nt)
#pragma unroll
      for (int rr = 0; rr < 4; ++rr) {
        int row = mt * 16 + q * 4 + rr;
        dst[row * 256 + n0 + nt * 16] = acc[mt][nt][rr] + bs[nt];
      }
}

// ---------------------------------------------------------------------------
// Kernel 3: persistent systolic grid. 192 blocks = (d, t, nh). Each walks s.
// ---------------------------------------------------------------------------
__global__ __launch_bounds__(256, 1) void grid_main(
    float* __restrict__ out, const float* __restrict__ bvec,
    char* __restrict__ ws) {
  __shared__ __align__(16) char lds[32 * 1040];
  const int bid = blockIdx.x;
  const int d = bid / 96;
  const int r = bid % 96;
  const int t = r >> 1, nh = r & 1;
  const int tid = threadIdx.x;
  const int w = tid >> 6, lane = tid & 63;
  const int alane = lane & 15, q = lane >> 4;

  int* flag0 = (int*)(ws + FLAG0_OFF);
  int* flag1 = (int*)(ws + FLAG1_OFF);
  const float* SRCW = (const float*)(ws + SRCW_OFF);
  const float* TRGW = (const float*)(ws + TRGW_OFF);

  short8 bu[2][16];
  {
    const char* ub = ws + UF_OFF + (size_t)((d * 2 + nh) * 4 + w) * 32768u + (size_t)lane * 16;
#pragma unroll
    for (int nt = 0; nt < 2; ++nt)
#pragma unroll
      for (int ks = 0; ks < 16; ++ks)
        bu[nt][ks] = *(const short8*)(ub + (nt * 16 + ks) * 1024);
  }
  short8 bw[2][8];
  float bs1[2] = {0.f, 0.f};
  if (d == 1) {
    const char* wb = ws + WF_OFF + (size_t)((2 + nh) * 4 + w) * 16384u + (size_t)lane * 16;
#pragma unroll
    for (int nt = 0; nt < 2; ++nt)
#pragma unroll
      for (int ks = 0; ks < 8; ++ks)
        bw[nt][ks] = *(const short8*)(wb + (nt * 8 + ks) * 1024);
    int bn = nh * 128 + w * 32 + alane;
    bs1[0] = bvec[256 + bn];
    bs1[1] = bvec[256 + bn + 16];
  }

  const char* ar0 = lds + alane * 1040 + q * 16;
  const char* ar1 = lds + (alane + 16) * 1040 + q * 16;
  const int n0 = nh * 128 + w * 32 + alane;
  const f32x4 zf = {0.f, 0.f, 0.f, 0.f};

  for (int s = 0; s < 48; ++s) {
    f32x4 acc[2][2];
    acc[0][0] = zf; acc[0][1] = zf; acc[1][0] = zf; acc[1][1] = zf;

    if (d == 0) {
      // Prefetch epilogue operands BEFORE the dependency wait (ws-resident,
      // peer-independent -> legal and off the critical path).
      float pfx[16], pfy[16];
      {
        const float* sxp = SRCW + (size_t)s * 8192;
        const float* syp = TRGW + (size_t)t * 8192;
#pragma unroll
        for (int mt = 0; mt < 2; ++mt)
#pragma unroll
          for (int nt = 0; nt < 2; ++nt)
#pragma unroll
            for (int rr = 0; rr < 4; ++rr) {
              int row = mt * 16 + q * 4 + rr;
              int n = n0 + nt * 16;
              pfx[(mt * 2 + nt) * 4 + rr] = sxp[row * 256 + n];
              pfy[(mt * 2 + nt) * 4 + rr] = syp[row * 256 + n];
            }
      }
      if (s > 0) wait_ge(&flag0[(s - 1) * 48 + t], 2);
      if (t > 0) wait_ge(&flag0[s * 48 + (t - 1)], 2);
      {  // stage A = [up | left], plain cached f32 loads -> bf16 -> LDS
        const float* pu = (s > 0) ? out + plane_off(0, s - 1, t, 0) : nullptr;
        const float* pl = (t > 0) ? out + plane_off(0, s, t - 1, 0) : nullptr;
#pragma unroll
        for (int it = 0; it < 8; ++it) {
          int gid = it * 256 + tid;
          int p = gid >> 10, row = (gid >> 5) & 31, c = gid & 31;
          const float* pp = p ? pl : pu;
          short8 v = {0, 0, 0, 0, 0, 0, 0, 0};
          if (pp) {
#pragma unroll
            for (int j = 0; j < 8; ++j) v[j] = f2bf(pp[row * 256 + c * 8 + j]);
          }
          *(short8*)(lds + row * 1040 + (p * 32 + c) * 16) = v;
        }
      }
      __syncthreads();
#pragma unroll
      for (int ks = 0; ks < 16; ++ks) {
        short8 a0 = *(const short8*)(ar0 + ks * 64);
        short8 a1 = *(const short8*)(ar1 + ks * 64);
#pragma unroll
        for (int nt = 0; nt < 2; ++nt) {
          acc[0][nt] = MFMA16(a0, bu[nt][ks], acc[0][nt]);
          acc[1][nt] = MFMA16(a1, bu[nt][ks], acc[1][nt]);
        }
      }
      float* hxp = out + plane_off(0, s, t, 0);
      float* hyp = out + plane_off(0, s, t, 1);
#pragma unroll
      for (int mt = 0; mt < 2; ++mt)
#pragma unroll
        for (int nt = 0; nt < 2; ++nt)
#pragma unroll
          for (int rr = 0; rr < 4; ++rr) {
            int row = mt * 16 + q * 4 + rr;
            int n = n0 + nt * 16;
            int i = (mt * 2 + nt) * 4 + rr;
            float tv = acc[mt][nt][rr];
            st_llc(&hxp[row * 256 + n], fast_tanh(pfx[i] + tv));
            st_llc(&hyp[row * 256 + n], fast_tanh(pfy[i] + tv));
          }
    } else {
      // --- layer 1: X/Y projections first (layer-0 runs ~2 hops ahead) ---
      wait_ge(&flag0[s * 48 + t], 2);
      {  // stage [hx0 | hy0]
        const float* px = out + plane_off(0, s, t, 0);
        const float* py = out + plane_off(0, s, t, 1);
#pragma unroll
        for (int it = 0; it < 8; ++it) {
          int gid = it * 256 + tid;
          int p = gid >> 10, row = (gid >> 5) & 31, c = gid & 31;
          const float* pp = p ? py : px;
          short8 v;
#pragma unroll
          for (int j = 0; j < 8; ++j) v[j] = f2bf(pp[row * 256 + c * 8 + j]);
          *(short8*)(lds + row * 1040 + (p * 32 + c) * 16) = v;
        }
      }
      __syncthreads();
      f32x4 accx[2][2], accy[2][2];
      accx[0][0] = zf; accx[0][1] = zf; accx[1][0] = zf; accx[1][1] = zf;
      accy[0][0] = zf; accy[0][1] = zf; accy[1][0] = zf; accy[1][1] = zf;
#pragma unroll
      for (int ks = 0; ks < 8; ++ks) {
        short8 ax0 = *(const short8*)(ar0 + ks * 64);
        short8 ax1 = *(const short8*)(ar1 + ks * 64);
        short8 ay0 = *(const short8*)(ar0 + 512 + ks * 64);
        short8 ay1 = *(const short8*)(ar1 + 512 + ks * 64);
#pragma unroll
        for (int nt = 0; nt < 2; ++nt) {
          accx[0][nt] = MFMA16(ax0, bw[nt][ks], accx[0][nt]);
          accx[1][nt] = MFMA16(ax1, bw[nt][ks], accx[1][nt]);
          accy[0][nt] = MFMA16(ay0, bw[nt][ks], accy[0][nt]);
          accy[1][nt] = MFMA16(ay1, bw[nt][ks], accy[1][nt]);
        }
      }
      __syncthreads();  // done reading LDS; safe to restage
      if (s > 0) wait_ge(&flag1[(s - 1) * 48 + t], 2);
      if (t > 0) wait_ge(&flag1[s * 48 + (t - 1)], 2);
      {  // stage A = [up1 | left1]
        const float* pu = (s > 0) ? out + plane_off(1, s - 1, t, 0) : nullptr;
        const float* pl = (t > 0) ? out + plane_off(1, s, t - 1, 0) : nullptr;
#pragma unroll
        for (int it = 0; it < 8; ++it) {
          int gid = it * 256 + tid;
          int p = gid >> 10, row = (gid >> 5) & 31, c = gid & 31;
          const float* pp = p ? pl : pu;
          short8 v = {0, 0, 0, 0, 0, 0, 0, 0};
          if (pp) {
#pragma unroll
            for (int j = 0; j < 8; ++j) v[j] = f2bf(pp[row * 256 + c * 8 + j]);
          }
          *(short8*)(lds + row * 1040 + (p * 32 + c) * 16) = v;
        }
      }
      __syncthreads();
#pragma unroll
      for (int ks = 0; ks < 16; ++ks) {
        short8 a0 = *(const short8*)(ar0 + ks * 64);
        short8 a1 = *(const short8*)(ar1 + ks * 64);
#pragma unroll
        for (int nt = 0; nt < 2; ++nt) {
          acc[0][nt] = MFMA16(a0, bu[nt][ks], acc[0][nt]);
          acc[1][nt] = MFMA16(a1, bu[nt][ks], acc[1][nt]);
        }
      }
      float* hxp = out + plane_off(1, s, t, 0);
      float* hyp = out + plane_off(1, s, t, 1);
#pragma unroll
      for (int mt = 0; mt < 2; ++mt)
#pragma unroll
        for (int nt = 0; nt < 2; ++nt)
#pragma unroll
          for (int rr = 0; rr < 4; ++rr) {
            int row = mt * 16 + q * 4 + rr;
            int n = n0 + nt * 16;
            float tv = acc[mt][nt][rr];
            // hx1 is consumed by peers -> bypass; hy1 is final-output-only.
            st_llc(&hxp[row * 256 + n], fast_tanh(accx[mt][nt][rr] + tv + bs1[nt]));
            hyp[row * 256 + n] = fast_tanh(accy[mt][nt][rr] + tv + bs1[nt]);
          }
    }
    // Drain this wave's (bypass) stores to the LLC, then barrier, then flag.
    asm volatile("s_waitcnt vmcnt(0)" ::: "memory");
    __syncthreads();
    if (tid == 0) {
      int* fp = (d == 0) ? &flag0[s * 48 + t] : &flag1[s * 48 + t];
      __hip_atomic_fetch_add(fp, 1, __ATOMIC_RELAXED, __HIP_MEMORY_SCOPE_AGENT);
    }
  }
}

extern "C" void kernel_launch(void* const* d_in, const int* in_sizes, int n_in,
                              void* d_out, int out_size, void* d_ws, size_t ws_size,
                              hipStream_t stream) {
  const float* src = (const float*)d_in[0];
  const float* trg = (const float*)d_in[1];
  const float* W   = (const float*)d_in[2];
  const float* U   = (const float*)d_in[3];
  const float* bv  = (const float*)d_in[4];
  float* out = (float*)d_out;
  char* ws = (char*)d_ws;

  hipMemsetAsync(ws + FLAG0_OFF, 0, 2u * 48 * 48 * 4, stream);
  preswizzle<<<192, 256, 0, stream>>>(U, W, ws);
  precompute_xw<<<192, 256, 0, stream>>>(src, trg, bv, ws);
  grid_main<<<192, 256, 0, stream>>>(out, bv, ws);
}